// Round 6
// baseline (679.051 us; speedup 1.0000x reference)
//
#include <hip/hip_runtime.h>
#include <hip/hip_bf16.h>
#include <math.h>

#define B_ 8
#define S_ 1024
#define D_ 1024
#define H_ 16
#define DH_ 64
#define FFN_ 4096
#define NEG_ (-1e9f)
#define EPS_ 1e-5f

typedef float f32x4 __attribute__((ext_vector_type(4)));
typedef short bf16x8 __attribute__((ext_vector_type(8)));

__device__ __forceinline__ ushort f2b(float f) {
  __hip_bfloat16 h = __float2bfloat16(f);  // RNE
  return *reinterpret_cast<ushort*>(&h);
}
__device__ __forceinline__ float b2f(ushort u) {
  return __uint_as_float((unsigned)u << 16);
}

__device__ __forceinline__ void gload16(const void* g, void* l) {
  auto* lp = (__attribute__((address_space(3))) unsigned*)(uintptr_t)(l);
  __builtin_amdgcn_global_load_lds(
      (const __attribute__((address_space(1))) unsigned*)g, lp, 16, 0, 0);
}

// XOR swizzle for [*][64]-ushort LDS tiles (128B row stride)
__device__ __forceinline__ void* swz_ptr(void* base, int row, int col) {
  int byte = (row << 7) + (col << 1);
  byte ^= (row & 7) << 4;
  return (char*)base + byte;
}

// ---------------------------------------------------------------------------
// casts / packing
// ---------------------------------------------------------------------------
__global__ __launch_bounds__(256) void cast_bf16_k(const float* __restrict__ in,
                                                   ushort* __restrict__ out,
                                                   int n4) {
  int i = blockIdx.x * 256 + threadIdx.x;
  if (i >= n4) return;
  float4 v = ((const float4*)in)[i];
  ushort4 o;
  o.x = f2b(v.x); o.y = f2b(v.y); o.z = f2b(v.z); o.w = f2b(v.w);
  ((ushort4*)out)[i] = o;
}

// qkvT[(which*1024 + h*64 + e)][k] = W{q,k,v}[h][k][e]   (bf16 out)
__global__ __launch_bounds__(256) void pack_qkvT_k(
    const float* __restrict__ Wq, const float* __restrict__ Wk,
    const float* __restrict__ Wv, ushort* __restrict__ out) {
  int idx = blockIdx.x * 256 + threadIdx.x;  // 3*16*1024*64
  int e = idx & 63, k = (idx >> 6) & 1023;
  int h = (idx >> 16) & 15, which = idx >> 20;
  const float* W = (which == 0) ? Wq : (which == 1 ? Wk : Wv);
  float v = W[((size_t)h * D_ + k) * DH_ + e];
  out[((size_t)which * 1024 + h * 64 + e) * 1024 + k] = f2b(v);
}

// ---------------------------------------------------------------------------
// 256x256 8-phase bf16 MFMA GEMM (T2 swizzle + T3/T4 counted vmcnt + T5).
// C[M][N] = act(A[M][K] @ Bt[N][K]^T + bias). 512 thr = 8 waves (2Mx4N),
// BK=64, 2 LDS buffers, fragment read-ahead one phase, quadrant order
// (0,0),(0,1),(1,1),(1,0). VSPLIT: QKV epilogue (Q,K -> C stride 2048,
// V -> vT[b][h][e][s]).
// ---------------------------------------------------------------------------
template <int BIAS, int RELU, int VSPLIT, int OUT_BF16>
__global__ __launch_bounds__(512, 2) void gemm256(
    const ushort* __restrict__ A, const ushort* __restrict__ Bt,
    const float* __restrict__ bias, void* __restrict__ C,
    ushort* __restrict__ vT, int M, int N, int K) {
  __shared__ ushort lds[2][2][256 * 64];  // [buf][0=A,1=B], 128 KiB
  const int nbn = N >> 8;
  const int nwg = gridDim.x;
  const int cpx = nwg >> 3;
  const int bid = blockIdx.x;
  const int swz = (bid & 7) * cpx + (bid >> 3);  // XCD-contiguous (nwg%8==0)
  const int bm = swz / nbn, bn = swz % nbn;

  const int t = threadIdx.x;
  const int lane = t & 63, lr = lane & 15, lg = lane >> 4;
  const int wid = t >> 6, wr = wid >> 2, wc = wid & 3;
  const size_t Kb = (size_t)K * 2;
  const char* Ab = (const char*)A + ((size_t)(bm << 8)) * Kb;
  const char* Bb = (const char*)Bt + ((size_t)(bn << 8)) * Kb;
  const int nt = K >> 6;
  const int niter = nt >> 1;

  // staging constants (linear LDS dest, pre-swizzled global source)
  const int srow = t >> 3;
  const int dib = (t & 7) << 4;
  const int sib = dib ^ ((srow & 7) << 4);

  auto STG = [&](int mat, int buf, int rowbase, int ktile) {
    int row = rowbase + srow;
    int k0b = (ktile % nt) << 7;
    const char* src = (mat ? Bb : Ab) + (size_t)row * Kb + k0b + sib;
    char* dst = (char*)&lds[buf][mat][0] + (row << 7) + dib;
    gload16(src, dst);
  };

  // fragment-read constants
  const int kswz = (lr & 7) << 3;  // ushort-index swizzle
  const int arow0 = wr * 128 + lr;
  const int brow0 = wc * 64 + lr;
  const int kb0 = lg * 8;

  bf16x8 aS[2][4][2], bS[2][2][2];
  f32x4 acc[8][4] = {};

  // prologue: tile0 -> buf0 (8 granules), tile1 -> buf1 (A02,A13,B01)
  STG(0, 0, 0, 0);   STG(0, 0, 128, 0); STG(0, 0, 64, 0);  STG(0, 0, 192, 0);
  STG(1, 0, 0, 0);   STG(1, 0, 64, 0);  STG(1, 0, 128, 0); STG(1, 0, 192, 0);
  STG(0, 1, 0, 1);   STG(0, 1, 128, 1); STG(0, 1, 64, 1);  STG(0, 1, 192, 1);
  STG(1, 1, 0, 1);   STG(1, 1, 64, 1);
  asm volatile("s_waitcnt vmcnt(6)" ::: "memory");
  __builtin_amdgcn_s_barrier();
  // read Q1(buf0) fragments into set 1
#pragma unroll
  for (int mm = 0; mm < 4; mm++)
#pragma unroll
    for (int kh = 0; kh < 2; kh++)
      aS[1][mm][kh] = *(const bf16x8*)
          &lds[0][0][((arow0 + mm * 16) << 6) + ((kb0 + kh * 32) ^ kswz)];
#pragma unroll
  for (int nn = 0; nn < 2; nn++)
#pragma unroll
    for (int kh = 0; kh < 2; kh++)
      bS[1][nn][kh] = *(const bf16x8*)
          &lds[0][1][((brow0 + nn * 16) << 6) + ((kb0 + kh * 32) ^ kswz)];

  for (int i = 0; i < niter; i++) {
    const int t1 = 2 * i + 1, t2 = 2 * i + 2, t3 = 2 * i + 3;
#pragma unroll
    for (int p = 0; p < 8; p++) {
      // --- read next quadrant's fragments (read-ahead) ---
      const int qr = (p + 1) & 3;
      const int rb = (p <= 2 || p == 7) ? 0 : 1;
      const int se = p & 1;
      const int qmr = (qr >= 2) ? 1 : 0;
      const int qnr = (qr == 1 || qr == 2) ? 1 : 0;
#pragma unroll
      for (int mm = 0; mm < 4; mm++)
#pragma unroll
        for (int kh = 0; kh < 2; kh++)
          aS[se][mm][kh] = *(const bf16x8*)
              &lds[rb][0][((arow0 + (qmr * 4 + mm) * 16) << 6) +
                          ((kb0 + kh * 32) ^ kswz)];
#pragma unroll
      for (int nn = 0; nn < 2; nn++)
#pragma unroll
        for (int kh = 0; kh < 2; kh++)
          bS[se][nn][kh] = *(const bf16x8*)
              &lds[rb][1][((brow0 + (qnr * 2 + nn) * 16) << 6) +
                          ((kb0 + kh * 32) ^ kswz)];
      // --- stage granules per schedule ---
      if (p == 0) { STG(1, 1, 128, t1); STG(1, 1, 192, t1); }
      if (p == 1) { STG(0, 0, 0, t2);   STG(0, 0, 128, t2); }
      if (p == 3) { STG(0, 0, 64, t2);  STG(0, 0, 192, t2); }
      if (p == 4) { STG(1, 0, 0, t2);   STG(1, 0, 64, t2); }
      if (p == 5) { STG(1, 0, 128, t2); STG(1, 0, 192, t2);
                    STG(0, 1, 0, t3);   STG(0, 1, 128, t3); }
      if (p == 7) { STG(0, 1, 64, t3);  STG(0, 1, 192, t3);
                    STG(1, 1, 0, t3);   STG(1, 1, 64, t3); }
      __builtin_amdgcn_s_barrier();
      // --- MFMA current quadrant from previous phase's fragments ---
      const int qd = p & 3;
      const int ms = (p + 1) & 1;
      const int qm = (qd >= 2) ? 1 : 0;
      const int qn = (qd == 1 || qd == 2) ? 1 : 0;
      __builtin_amdgcn_s_setprio(1);
#pragma unroll
      for (int mm = 0; mm < 4; mm++)
#pragma unroll
        for (int nn = 0; nn < 2; nn++)
#pragma unroll
          for (int kh = 0; kh < 2; kh++)
            acc[qm * 4 + mm][qn * 2 + nn] =
                __builtin_amdgcn_mfma_f32_16x16x32_bf16(
                    aS[ms][mm][kh], bS[ms][nn][kh],
                    acc[qm * 4 + mm][qn * 2 + nn], 0, 0, 0);
      __builtin_amdgcn_s_setprio(0);
      // retire this phase's ds_reads before end barrier (overwrite safety)
      asm volatile("s_waitcnt lgkmcnt(0)" ::: "memory");
      __builtin_amdgcn_sched_barrier(0);
      if (p == 2 || p == 6)
        asm volatile("s_waitcnt vmcnt(2)" ::: "memory");
      __builtin_amdgcn_s_barrier();
    }
  }
  asm volatile("s_waitcnt vmcnt(0)" ::: "memory");

  // epilogue
  const int r0 = (bm << 8) + wr * 128 + lg * 4;
  const int c0 = (bn << 8) + wc * 64 + lr;
#pragma unroll
  for (int m = 0; m < 8; m++)
#pragma unroll
    for (int n = 0; n < 4; n++) {
      int col = c0 + n * 16;
      float bv = BIAS ? bias[col] : 0.0f;
#pragma unroll
      for (int q = 0; q < 4; q++) {
        int row = r0 + m * 16 + q;
        float v = acc[m][n][q] + bv;
        if (RELU) v = fmaxf(v, 0.0f);
        if (VSPLIT) {
          if (col < 2048) {
            ((ushort*)C)[(size_t)row * 2048 + col] = f2b(v);
          } else {
            int h = (col - 2048) >> 6, e = col & 63;
            vT[((((size_t)(row >> 10) * 16 + h) * 64 + e) << 10) +
               (row & 1023)] = f2b(v);
          }
        } else if (OUT_BF16) {
          ((ushort*)C)[(size_t)row * N + col] = f2b(v);
        } else {
          ((float*)C)[(size_t)row * N + col] = v;
        }
      }
    }
}

// ---------------------------------------------------------------------------
// bf16 MFMA GEMM (m97 structure): C[M][N] = act(A[M][K] @ Bt[N][K]^T + bias)
// 128x128 tile, BK=64, 256 thr = 4 waves (2x2). Used for N=1024 GEMMs.
// ---------------------------------------------------------------------------
template <int BIAS, int RELU, int OUT_BF16>
__global__ __launch_bounds__(256) void gemm_bf16(
    const ushort* __restrict__ A, const ushort* __restrict__ Bt,
    const float* __restrict__ bias, void* __restrict__ C,
    int M, int N, int K) {
  __shared__ ushort Al[128 * 64];
  __shared__ ushort Bl[128 * 64];
  const int nb = N >> 7;
  const int bm = blockIdx.x / nb, bn = blockIdx.x % nb;
  const int t = threadIdx.x;
  const int lane = t & 63;
  const int wid = t >> 6, wr = wid >> 1, wc = wid & 1;
  const int row0 = bm << 7, col0 = bn << 7;
  const size_t Kb = (size_t)K * 2;

  const char* Abase = (const char*)A + (size_t)row0 * Kb;
  const char* Bbase = (const char*)Bt + (size_t)col0 * Kb;

  f32x4 acc[4][4] = {};

  const int o0 = t * 16;
  for (int k0 = 0; k0 < K; k0 += 64) {
#pragma unroll
    for (int i = 0; i < 4; i++) {
      int ob = o0 + i * 4096;
      int row = ob >> 7, inrow = ob & 127;
      const char* ga = Abase + (size_t)row * Kb + k0 * 2 + inrow;
      const char* gb = Bbase + (size_t)row * Kb + k0 * 2 + inrow;
      gload16(ga, (char*)Al + ob);
      gload16(gb, (char*)Bl + ob);
    }
    __syncthreads();
#pragma unroll
    for (int kk = 0; kk < 64; kk += 32) {
      bf16x8 af[4], bfr[4];
      const int lrow = lane & 15, lk = (lane >> 4) * 8 + kk;
#pragma unroll
      for (int m = 0; m < 4; m++)
        af[m] = *(const bf16x8*)&Al[(wr * 64 + m * 16 + lrow) * 64 + lk];
#pragma unroll
      for (int n = 0; n < 4; n++)
        bfr[n] = *(const bf16x8*)&Bl[(wc * 64 + n * 16 + lrow) * 64 + lk];
#pragma unroll
      for (int m = 0; m < 4; m++)
#pragma unroll
        for (int n = 0; n < 4; n++)
          acc[m][n] = __builtin_amdgcn_mfma_f32_16x16x32_bf16(
              af[m], bfr[n], acc[m][n], 0, 0, 0);
    }
    __syncthreads();
  }

  const int rbase = row0 + wr * 64 + (lane >> 4) * 4;
  const int cbase = col0 + wc * 64 + (lane & 15);
#pragma unroll
  for (int m = 0; m < 4; m++) {
#pragma unroll
    for (int n = 0; n < 4; n++) {
      int col = cbase + n * 16;
      float bv = BIAS ? bias[col] : 0.0f;
#pragma unroll
      for (int q = 0; q < 4; q++) {
        int row = rbase + m * 16 + q;
        float v = acc[m][n][q] + bv;
        if (RELU) v = fmaxf(v, 0.0f);
        if (OUT_BF16)
          ((ushort*)C)[(size_t)row * N + col] = f2b(v);
        else
          ((float*)C)[(size_t)row * N + col] = v;
      }
    }
  }
}

// ---------------------------------------------------------------------------
// MFMA flash attention. Inputs: qk [B*S][2048] (q|k per head), vT [B][H][64][S]
// (V pre-transposed by the QKV GEMM). One block per (b, h, 64 q-rows).
// ---------------------------------------------------------------------------
__global__ __launch_bounds__(256) void attention_mfma_k(
    const ushort* __restrict__ qk, const ushort* __restrict__ vT,
    const int* __restrict__ lens, ushort* __restrict__ concat) {
  __shared__ ushort Qs[64 * 64];
  __shared__ ushort Ks[64 * 64];
  __shared__ ushort Vt[64 * 64];      // [d][key]
  __shared__ ushort Pl[4][16 * 64];   // per-wave P tile [qrow][key]
  const int blk = blockIdx.x;
  const int b = blk >> 8, rem = blk & 255;
  const int h = rem >> 4, q0 = (rem & 15) << 6;
  const int t = threadIdx.x;
  const int lane = t & 63, w = t >> 6;
  const int lr = lane & 15, lg = lane >> 4;
  const int len_b = lens[b];
  ushort* Plw = &Pl[w][0];
  const ushort* vbase = vT + ((size_t)(b * 16 + h) << 16);  // [64][1024]

  // load Q tile (row-major, swizzled)
#pragma unroll
  for (int i = 0; i < 4; i++) {
    int idx = t + i * 256;
    int r = idx >> 4, eq = idx & 15;
    const ushort* src =
        qk + ((size_t)(b * S_ + q0 + r)) * 2048 + h * 64 + eq * 4;
    *(ushort4*)swz_ptr(Qs, r, eq * 4) = *(const ushort4*)src;
  }
  __syncthreads();
  bf16x8 qf[2];
#pragma unroll
  for (int ds = 0; ds < 2; ds++)
    qf[ds] = *(const bf16x8*)swz_ptr(Qs, w * 16 + lr, lg * 8 + ds * 32);

  float m[4], l[4];
  f32x4 o[4] = {};
#pragma unroll
  for (int q = 0; q < 4; q++) { m[q] = -INFINITY; l[q] = 0.f; }

  for (int j0 = 0; j0 < len_b; j0 += 64) {
    __syncthreads();
    // K tile (row-major, swizzled) + V^T tile (vector loads from vT)
#pragma unroll
    for (int i = 0; i < 4; i++) {
      int idx = t + i * 256;
      int r = idx >> 4, eq = idx & 15;
      const ushort* ksrc =
          qk + ((size_t)(b * S_ + j0 + r)) * 2048 + 1024 + h * 64 + eq * 4;
      *(ushort4*)swz_ptr(Ks, r, eq * 4) = *(const ushort4*)ksrc;
      *(ushort4*)swz_ptr(Vt, r, eq * 4) =
          *(const ushort4*)(vbase + (size_t)r * 1024 + j0 + eq * 4);
    }
    __syncthreads();

    // QK^T
    f32x4 sacc[4];
#pragma unroll
    for (int n = 0; n < 4; n++) {
      sacc[n] = (f32x4){0.f, 0.f, 0.f, 0.f};
#pragma unroll
      for (int ds = 0; ds < 2; ds++) {
        bf16x8 kf = *(const bf16x8*)swz_ptr(Ks, n * 16 + lr, lg * 8 + ds * 32);
        sacc[n] = __builtin_amdgcn_mfma_f32_16x16x32_bf16(qf[ds], kf, sacc[n],
                                                          0, 0, 0);
      }
    }

    // scale + mask + online softmax
    float p[4][4];
#pragma unroll
    for (int q = 0; q < 4; q++) {
      float s[4];
#pragma unroll
      for (int n = 0; n < 4; n++) {
        s[n] = sacc[n][q] * 0.125f;
        if (j0 + n * 16 + lr >= len_b) s[n] = NEG_;
      }
      float a = fmaxf(fmaxf(s[0], s[1]), fmaxf(s[2], s[3]));
#pragma unroll
      for (int off = 1; off < 16; off <<= 1) a = fmaxf(a, __shfl_xor(a, off));
      float mn = fmaxf(m[q], a);
      float sc = __expf(m[q] - mn);
      float rs = 0.f;
#pragma unroll
      for (int n = 0; n < 4; n++) {
        p[n][q] = __expf(s[n] - mn);
        rs += p[n][q];
      }
#pragma unroll
      for (int off = 1; off < 16; off <<= 1) rs += __shfl_xor(rs, off);
      l[q] = l[q] * sc + rs;
      m[q] = mn;
#pragma unroll
      for (int dt = 0; dt < 4; dt++) o[dt][q] *= sc;
    }

    // P -> bf16 -> per-wave LDS
#pragma unroll
    for (int n = 0; n < 4; n++)
#pragma unroll
      for (int q = 0; q < 4; q++)
        *(ushort*)swz_ptr(Plw, lg * 4 + q, n * 16 + lr) = f2b(p[n][q]);

    // PV
    bf16x8 pf[2];
#pragma unroll
    for (int ks = 0; ks < 2; ks++)
      pf[ks] = *(const bf16x8*)swz_ptr(Plw, lr, lg * 8 + ks * 32);
#pragma unroll
    for (int dt = 0; dt < 4; dt++) {
#pragma unroll
      for (int ks = 0; ks < 2; ks++) {
        bf16x8 vf = *(const bf16x8*)swz_ptr(Vt, dt * 16 + lr, lg * 8 + ks * 32);
        o[dt] = __builtin_amdgcn_mfma_f32_16x16x32_bf16(pf[ks], vf, o[dt],
                                                        0, 0, 0);
      }
    }
  }

#pragma unroll
  for (int q = 0; q < 4; q++) {
    float inv = 1.0f / l[q];
    size_t row = (size_t)(b * S_ + q0 + w * 16 + lg * 4 + q);
#pragma unroll
    for (int dt = 0; dt < 4; dt++)
      concat[row * 1024 + h * 64 + dt * 16 + lr] = f2b(o[dt][q] * inv);
  }
}

// ---------------------------------------------------------------------------
// y = LayerNorm(a + r); optionally also write bf16 copy yb
// ---------------------------------------------------------------------------
template <int WBF>
__global__ __launch_bounds__(256) void add_ln_k(const float* __restrict__ a,
                                                const float* __restrict__ r,
                                                float* __restrict__ y,
                                                ushort* __restrict__ yb) {
  const int row = blockIdx.x, t = threadIdx.x;
  const float4 av = ((const float4*)(a + (size_t)row * 1024))[t];
  const float4 rv = ((const float4*)(r + (size_t)row * 1024))[t];
  float v[4] = {av.x + rv.x, av.y + rv.y, av.z + rv.z, av.w + rv.w};
  float s = v[0] + v[1] + v[2] + v[3];
  float q = v[0] * v[0] + v[1] * v[1] + v[2] * v[2] + v[3] * v[3];
#pragma unroll
  for (int off = 1; off < 64; off <<= 1) {
    s += __shfl_xor(s, off);
    q += __shfl_xor(q, off);
  }
  __shared__ float ss[4], sq[4];
  int wave = t >> 6, lane = t & 63;
  if (lane == 0) { ss[wave] = s; sq[wave] = q; }
  __syncthreads();
  s = ss[0] + ss[1] + ss[2] + ss[3];
  q = sq[0] + sq[1] + sq[2] + sq[3];
  float mean = s * (1.f / 1024.f);
  float var = q * (1.f / 1024.f) - mean * mean;
  float inv = 1.0f / sqrtf(var + EPS_);
  float4 yo;
  yo.x = (v[0] - mean) * inv; yo.y = (v[1] - mean) * inv;
  yo.z = (v[2] - mean) * inv; yo.w = (v[3] - mean) * inv;
  ((float4*)(y + (size_t)row * 1024))[t] = yo;
  if (WBF) {
    ushort4 ob;
    ob.x = f2b(yo.x); ob.y = f2b(yo.y); ob.z = f2b(yo.z); ob.w = f2b(yo.w);
    ((ushort4*)(yb + (size_t)row * 1024))[t] = ob;
  }
}

// ---------------------------------------------------------------------------
extern "C" void kernel_launch(void* const* d_in, const int* in_sizes, int n_in,
                              void* d_out, int out_size, void* d_ws, size_t ws_size,
                              hipStream_t stream) {
  const float* x  = (const float*)d_in[0];
  const int* len  = (const int*)d_in[1];
  const float* Wq = (const float*)d_in[2];
  const float* Wk = (const float*)d_in[3];
  const float* Wv = (const float*)d_in[4];
  const float* Wo = (const float*)d_in[5];
  const float* W1 = (const float*)d_in[6];
  const float* b1 = (const float*)d_in[7];
  const float* W2 = (const float*)d_in[8];
  const float* b2 = (const float*)d_in[9];
  float* out = (float*)d_out;

  if (ws_size < (size_t)184 * 1024 * 1024) return;
  char* w = (char*)d_ws;
  ushort* xbf    = (ushort*)(w);                        // 16MB
  ushort* qkvw   = (ushort*)(w + ((size_t)16 << 20));   // 6MB
  ushort* wob    = (ushort*)(w + ((size_t)22 << 20));   // 2MB
  ushort* w1b    = (ushort*)(w + ((size_t)24 << 20));   // 8MB
  ushort* w2b    = (ushort*)(w + ((size_t)32 << 20));   // 8MB
  ushort* qk2    = (ushort*)(w + ((size_t)40 << 20));   // 32MB  [8192][2048]
  ushort* vT     = (ushort*)(w + ((size_t)72 << 20));   // 16MB  [8][16][64][1024]
  ushort* concat = (ushort*)(w + ((size_t)88 << 20));   // 16MB
  float*  attno  = (float*) (w + ((size_t)104 << 20));  // 32MB
  float*  x1     = (float*) (w + ((size_t)136 << 20));  // 32MB
  ushort* x1b    = (ushort*)(w + ((size_t)168 << 20));  // 16MB
  ushort* hidden = (ushort*)(w + ((size_t)40 << 20));   // 64MB (reuse qk2+vT+concat)
  float*  ffn2o  = (float*) (w + ((size_t)104 << 20));  // 32MB (reuse attno)

  cast_bf16_k<<<8192, 256, 0, stream>>>(x, xbf, 2097152);
  pack_qkvT_k<<<12288, 256, 0, stream>>>(Wq, Wk, Wv, qkvw);
  cast_bf16_k<<<1024, 256, 0, stream>>>(Wo, wob, 262144);
  cast_bf16_k<<<4096, 256, 0, stream>>>(W1, w1b, 1048576);
  cast_bf16_k<<<4096, 256, 0, stream>>>(W2, w2b, 1048576);

  // QKV projection (8-phase 256^2): Q,K -> qk2 (stride 2048), V -> vT
  gemm256<0, 0, 1, 1><<<32 * 12, 512, 0, stream>>>(xbf, qkvw, nullptr, qk2,
                                                   vT, 8192, 3072, 1024);
  attention_mfma_k<<<2048, 256, 0, stream>>>(qk2, vT, len, concat);
  // output projection -> fp32 (m97 128^2)
  gemm_bf16<0, 0, 0><<<64 * 8, 256, 0, stream>>>(concat, wob, nullptr, attno,
                                                 8192, 1024, 1024);
  add_ln_k<1><<<8192, 256, 0, stream>>>(x, attno, x1, x1b);
  // FFN1 + bias + relu -> bf16 (8-phase 256^2)
  gemm256<1, 1, 0, 1><<<32 * 16, 512, 0, stream>>>(x1b, w1b, b1, hidden,
                                                   nullptr, 8192, 4096, 1024);
  // FFN2 + bias -> fp32 (m97 128^2)
  gemm_bf16<1, 0, 0><<<64 * 8, 256, 0, stream>>>(hidden, w2b, b2, ffn2o,
                                                 8192, 1024, 4096);
  add_ln_k<0><<<8192, 256, 0, stream>>>(x1, ffn2o, out, nullptr);
}

// Round 7
// 502.961 us; speedup vs baseline: 1.3501x; 1.3501x over previous
//
#include <hip/hip_runtime.h>
#include <hip/hip_bf16.h>
#include <math.h>

#define B_ 8
#define S_ 1024
#define D_ 1024
#define H_ 16
#define DH_ 64
#define FFN_ 4096
#define NEG_ (-1e9f)
#define EPS_ 1e-5f

typedef float f32x4 __attribute__((ext_vector_type(4)));
typedef short bf16x8 __attribute__((ext_vector_type(8)));

__device__ __forceinline__ ushort f2b(float f) {
  __hip_bfloat16 h = __float2bfloat16(f);  // RNE
  return *reinterpret_cast<ushort*>(&h);
}
__device__ __forceinline__ float b2f(ushort u) {
  return __uint_as_float((unsigned)u << 16);
}

__device__ __forceinline__ void gload16(const void* g, void* l) {
  auto* lp = (__attribute__((address_space(3))) unsigned*)(uintptr_t)(l);
  __builtin_amdgcn_global_load_lds(
      (const __attribute__((address_space(1))) unsigned*)g, lp, 16, 0, 0);
}

// XOR swizzle for [*][64]-ushort LDS tiles (128B row stride)
__device__ __forceinline__ void* swz_ptr(void* base, int row, int col) {
  int byte = (row << 7) + (col << 1);
  byte ^= (row & 7) << 4;
  return (char*)base + byte;
}

// ---------------------------------------------------------------------------
// casts / packing
// ---------------------------------------------------------------------------
__global__ __launch_bounds__(256) void cast_bf16_k(const float* __restrict__ in,
                                                   ushort* __restrict__ out,
                                                   int n4) {
  int i = blockIdx.x * 256 + threadIdx.x;
  if (i >= n4) return;
  float4 v = ((const float4*)in)[i];
  ushort4 o;
  o.x = f2b(v.x); o.y = f2b(v.y); o.z = f2b(v.z); o.w = f2b(v.w);
  ((ushort4*)out)[i] = o;
}

// qkvT[(which*1024 + h*64 + e)][k] = W{q,k,v}[h][k][e]   (bf16 out)
__global__ __launch_bounds__(256) void pack_qkvT_k(
    const float* __restrict__ Wq, const float* __restrict__ Wk,
    const float* __restrict__ Wv, ushort* __restrict__ out) {
  int idx = blockIdx.x * 256 + threadIdx.x;  // 3*16*1024*64
  int e = idx & 63, k = (idx >> 6) & 1023;
  int h = (idx >> 16) & 15, which = idx >> 20;
  const float* W = (which == 0) ? Wq : (which == 1 ? Wk : Wv);
  float v = W[((size_t)h * D_ + k) * DH_ + e];
  out[((size_t)which * 1024 + h * 64 + e) * 1024 + k] = f2b(v);
}

// ---------------------------------------------------------------------------
// bf16 MFMA GEMM (m97 structure): C[M][N] = act(A[M][K] @ Bt[N][K]^T + bias)
// 128x128 tile, BK=64, 256 thr = 4 waves (2x2), 64x64 per wave.
// VSPLIT (QKV): cols<2048 -> C stride 2048 (q|k); cols>=2048 -> vT[b][h][e][s].
// ---------------------------------------------------------------------------
template <int BIAS, int RELU, int OUT_BF16, int VSPLIT>
__global__ __launch_bounds__(256) void gemm_bf16(
    const ushort* __restrict__ A, const ushort* __restrict__ Bt,
    const float* __restrict__ bias, void* __restrict__ C,
    ushort* __restrict__ vT, int M, int N, int K) {
  __shared__ ushort Al[128 * 64];
  __shared__ ushort Bl[128 * 64];
  const int nb = N >> 7;
  const int bm = blockIdx.x / nb, bn = blockIdx.x % nb;
  const int t = threadIdx.x;
  const int lane = t & 63;
  const int wid = t >> 6, wr = wid >> 1, wc = wid & 1;
  const int row0 = bm << 7, col0 = bn << 7;
  const size_t Kb = (size_t)K * 2;

  const char* Abase = (const char*)A + (size_t)row0 * Kb;
  const char* Bbase = (const char*)Bt + (size_t)col0 * Kb;

  f32x4 acc[4][4] = {};

  const int o0 = t * 16;
  for (int k0 = 0; k0 < K; k0 += 64) {
#pragma unroll
    for (int i = 0; i < 4; i++) {
      int ob = o0 + i * 4096;
      int row = ob >> 7, inrow = ob & 127;
      const char* ga = Abase + (size_t)row * Kb + k0 * 2 + inrow;
      const char* gb = Bbase + (size_t)row * Kb + k0 * 2 + inrow;
      gload16(ga, (char*)Al + ob);
      gload16(gb, (char*)Bl + ob);
    }
    __syncthreads();
#pragma unroll
    for (int kk = 0; kk < 64; kk += 32) {
      bf16x8 af[4], bfr[4];
      const int lrow = lane & 15, lk = (lane >> 4) * 8 + kk;
#pragma unroll
      for (int m = 0; m < 4; m++)
        af[m] = *(const bf16x8*)&Al[(wr * 64 + m * 16 + lrow) * 64 + lk];
#pragma unroll
      for (int n = 0; n < 4; n++)
        bfr[n] = *(const bf16x8*)&Bl[(wc * 64 + n * 16 + lrow) * 64 + lk];
#pragma unroll
      for (int m = 0; m < 4; m++)
#pragma unroll
        for (int n = 0; n < 4; n++)
          acc[m][n] = __builtin_amdgcn_mfma_f32_16x16x32_bf16(
              af[m], bfr[n], acc[m][n], 0, 0, 0);
    }
    __syncthreads();
  }

  const int rbase = row0 + wr * 64 + (lane >> 4) * 4;
  const int cbase = col0 + wc * 64 + (lane & 15);
#pragma unroll
  for (int m = 0; m < 4; m++) {
#pragma unroll
    for (int n = 0; n < 4; n++) {
      int col = cbase + n * 16;
      float bv = BIAS ? bias[col] : 0.0f;
#pragma unroll
      for (int q = 0; q < 4; q++) {
        int row = rbase + m * 16 + q;
        float v = acc[m][n][q] + bv;
        if (RELU) v = fmaxf(v, 0.0f);
        if (VSPLIT) {
          if (col < 2048) {
            ((ushort*)C)[(size_t)row * 2048 + col] = f2b(v);
          } else {
            int h = (col - 2048) >> 6, e = col & 63;
            vT[((((size_t)(row >> 10) * 16 + h) * 64 + e) << 10) +
               (row & 1023)] = f2b(v);
          }
        } else if (OUT_BF16) {
          ((ushort*)C)[(size_t)row * N + col] = f2b(v);
        } else {
          ((float*)C)[(size_t)row * N + col] = v;
        }
      }
    }
  }
}

// ---------------------------------------------------------------------------
// MFMA flash attention. Inputs: qk [B*S][2048] (q|k per head), vT [B][H][64][S]
// (V pre-transposed by the QKV GEMM). One block per (b, h, 64 q-rows).
// Block order batch-interleaved (b fastest) for length load-balance.
// ---------------------------------------------------------------------------
__global__ __launch_bounds__(256) void attention_mfma_k(
    const ushort* __restrict__ qk, const ushort* __restrict__ vT,
    const int* __restrict__ lens, ushort* __restrict__ concat) {
  __shared__ ushort Qs[64 * 64];
  __shared__ ushort Ks[64 * 64];
  __shared__ ushort Vt[64 * 64];      // [d][key]
  __shared__ ushort Pl[4][16 * 64];   // per-wave P tile [qrow][key]
  const int blk = blockIdx.x;
  const int b = blk & 7, h = (blk >> 3) & 15, q0 = (blk >> 7) << 6;
  const int t = threadIdx.x;
  const int lane = t & 63, w = t >> 6;
  const int lr = lane & 15, lg = lane >> 4;
  const int len_b = lens[b];
  ushort* Plw = &Pl[w][0];
  const ushort* vbase = vT + ((size_t)(b * 16 + h) << 16);  // [64][1024]

  // load Q tile (row-major, swizzled)
#pragma unroll
  for (int i = 0; i < 4; i++) {
    int idx = t + i * 256;
    int r = idx >> 4, eq = idx & 15;
    const ushort* src =
        qk + ((size_t)(b * S_ + q0 + r)) * 2048 + h * 64 + eq * 4;
    *(ushort4*)swz_ptr(Qs, r, eq * 4) = *(const ushort4*)src;
  }
  __syncthreads();
  bf16x8 qf[2];
#pragma unroll
  for (int ds = 0; ds < 2; ds++)
    qf[ds] = *(const bf16x8*)swz_ptr(Qs, w * 16 + lr, lg * 8 + ds * 32);

  float m[4], l[4];
  f32x4 o[4] = {};
#pragma unroll
  for (int q = 0; q < 4; q++) { m[q] = -INFINITY; l[q] = 0.f; }

  for (int j0 = 0; j0 < len_b; j0 += 64) {
    __syncthreads();
    // K tile (row-major, swizzled) + V^T tile (vector loads from vT)
#pragma unroll
    for (int i = 0; i < 4; i++) {
      int idx = t + i * 256;
      int r = idx >> 4, eq = idx & 15;
      const ushort* ksrc =
          qk + ((size_t)(b * S_ + j0 + r)) * 2048 + 1024 + h * 64 + eq * 4;
      *(ushort4*)swz_ptr(Ks, r, eq * 4) = *(const ushort4*)ksrc;
      *(ushort4*)swz_ptr(Vt, r, eq * 4) =
          *(const ushort4*)(vbase + (size_t)r * 1024 + j0 + eq * 4);
    }
    __syncthreads();

    // QK^T
    f32x4 sacc[4];
    __builtin_amdgcn_s_setprio(1);
#pragma unroll
    for (int n = 0; n < 4; n++) {
      sacc[n] = (f32x4){0.f, 0.f, 0.f, 0.f};
#pragma unroll
      for (int ds = 0; ds < 2; ds++) {
        bf16x8 kf = *(const bf16x8*)swz_ptr(Ks, n * 16 + lr, lg * 8 + ds * 32);
        sacc[n] = __builtin_amdgcn_mfma_f32_16x16x32_bf16(qf[ds], kf, sacc[n],
                                                          0, 0, 0);
      }
    }
    __builtin_amdgcn_s_setprio(0);

    // scale + mask + online softmax
    float p[4][4];
#pragma unroll
    for (int q = 0; q < 4; q++) {
      float s[4];
#pragma unroll
      for (int n = 0; n < 4; n++) {
        s[n] = sacc[n][q] * 0.125f;
        if (j0 + n * 16 + lr >= len_b) s[n] = NEG_;
      }
      float a = fmaxf(fmaxf(s[0], s[1]), fmaxf(s[2], s[3]));
#pragma unroll
      for (int off = 1; off < 16; off <<= 1) a = fmaxf(a, __shfl_xor(a, off));
      float mn = fmaxf(m[q], a);
      float sc = __expf(m[q] - mn);
      float rs = 0.f;
#pragma unroll
      for (int n = 0; n < 4; n++) {
        p[n][q] = __expf(s[n] - mn);
        rs += p[n][q];
      }
#pragma unroll
      for (int off = 1; off < 16; off <<= 1) rs += __shfl_xor(rs, off);
      l[q] = l[q] * sc + rs;
      m[q] = mn;
#pragma unroll
      for (int dt = 0; dt < 4; dt++) o[dt][q] *= sc;
    }

    // P -> bf16 -> per-wave LDS
#pragma unroll
    for (int n = 0; n < 4; n++)
#pragma unroll
      for (int q = 0; q < 4; q++)
        *(ushort*)swz_ptr(Plw, lg * 4 + q, n * 16 + lr) = f2b(p[n][q]);

    // PV
    bf16x8 pf[2];
#pragma unroll
    for (int ks = 0; ks < 2; ks++)
      pf[ks] = *(const bf16x8*)swz_ptr(Plw, lr, lg * 8 + ks * 32);
    __builtin_amdgcn_s_setprio(1);
#pragma unroll
    for (int dt = 0; dt < 4; dt++) {
#pragma unroll
      for (int ks = 0; ks < 2; ks++) {
        bf16x8 vf = *(const bf16x8*)swz_ptr(Vt, dt * 16 + lr, lg * 8 + ks * 32);
        o[dt] = __builtin_amdgcn_mfma_f32_16x16x32_bf16(pf[ks], vf, o[dt],
                                                        0, 0, 0);
      }
    }
    __builtin_amdgcn_s_setprio(0);
  }

#pragma unroll
  for (int q = 0; q < 4; q++) {
    float inv = 1.0f / l[q];
    size_t row = (size_t)(b * S_ + q0 + w * 16 + lg * 4 + q);
#pragma unroll
    for (int dt = 0; dt < 4; dt++)
      concat[row * 1024 + h * 64 + dt * 16 + lr] = f2b(o[dt][q] * inv);
  }
}

// ---------------------------------------------------------------------------
// y = LayerNorm(a + r); optionally also write bf16 copy yb
// ---------------------------------------------------------------------------
template <int WBF>
__global__ __launch_bounds__(256) void add_ln_k(const float* __restrict__ a,
                                                const float* __restrict__ r,
                                                float* __restrict__ y,
                                                ushort* __restrict__ yb) {
  const int row = blockIdx.x, t = threadIdx.x;
  const float4 av = ((const float4*)(a + (size_t)row * 1024))[t];
  const float4 rv = ((const float4*)(r + (size_t)row * 1024))[t];
  float v[4] = {av.x + rv.x, av.y + rv.y, av.z + rv.z, av.w + rv.w};
  float s = v[0] + v[1] + v[2] + v[3];
  float q = v[0] * v[0] + v[1] * v[1] + v[2] * v[2] + v[3] * v[3];
#pragma unroll
  for (int off = 1; off < 64; off <<= 1) {
    s += __shfl_xor(s, off);
    q += __shfl_xor(q, off);
  }
  __shared__ float ss[4], sq[4];
  int wave = t >> 6, lane = t & 63;
  if (lane == 0) { ss[wave] = s; sq[wave] = q; }
  __syncthreads();
  s = ss[0] + ss[1] + ss[2] + ss[3];
  q = sq[0] + sq[1] + sq[2] + sq[3];
  float mean = s * (1.f / 1024.f);
  float var = q * (1.f / 1024.f) - mean * mean;
  float inv = 1.0f / sqrtf(var + EPS_);
  float4 yo;
  yo.x = (v[0] - mean) * inv; yo.y = (v[1] - mean) * inv;
  yo.z = (v[2] - mean) * inv; yo.w = (v[3] - mean) * inv;
  ((float4*)(y + (size_t)row * 1024))[t] = yo;
  if (WBF) {
    ushort4 ob;
    ob.x = f2b(yo.x); ob.y = f2b(yo.y); ob.z = f2b(yo.z); ob.w = f2b(yo.w);
    ((ushort4*)(yb + (size_t)row * 1024))[t] = ob;
  }
}

// ---------------------------------------------------------------------------
extern "C" void kernel_launch(void* const* d_in, const int* in_sizes, int n_in,
                              void* d_out, int out_size, void* d_ws, size_t ws_size,
                              hipStream_t stream) {
  const float* x  = (const float*)d_in[0];
  const int* len  = (const int*)d_in[1];
  const float* Wq = (const float*)d_in[2];
  const float* Wk = (const float*)d_in[3];
  const float* Wv = (const float*)d_in[4];
  const float* Wo = (const float*)d_in[5];
  const float* W1 = (const float*)d_in[6];
  const float* b1 = (const float*)d_in[7];
  const float* W2 = (const float*)d_in[8];
  const float* b2 = (const float*)d_in[9];
  float* out = (float*)d_out;

  if (ws_size < (size_t)184 * 1024 * 1024) return;
  char* w = (char*)d_ws;
  ushort* xbf    = (ushort*)(w);                        // 16MB
  ushort* qkvw   = (ushort*)(w + ((size_t)16 << 20));   // 6MB
  ushort* wob    = (ushort*)(w + ((size_t)22 << 20));   // 2MB
  ushort* w1b    = (ushort*)(w + ((size_t)24 << 20));   // 8MB
  ushort* w2b    = (ushort*)(w + ((size_t)32 << 20));   // 8MB
  ushort* qk2    = (ushort*)(w + ((size_t)40 << 20));   // 32MB  [8192][2048]
  ushort* vT     = (ushort*)(w + ((size_t)72 << 20));   // 16MB  [8][16][64][1024]
  ushort* concat = (ushort*)(w + ((size_t)88 << 20));   // 16MB
  float*  attno  = (float*) (w + ((size_t)104 << 20));  // 32MB
  float*  x1     = (float*) (w + ((size_t)136 << 20));  // 32MB
  ushort* x1b    = (ushort*)(w + ((size_t)168 << 20));  // 16MB
  ushort* hidden = (ushort*)(w + ((size_t)40 << 20));   // 64MB (reuse qk2+vT+concat)
  float*  ffn2o  = (float*) (w + ((size_t)104 << 20));  // 32MB (reuse attno)

  cast_bf16_k<<<8192, 256, 0, stream>>>(x, xbf, 2097152);
  pack_qkvT_k<<<12288, 256, 0, stream>>>(Wq, Wk, Wv, qkvw);
  cast_bf16_k<<<1024, 256, 0, stream>>>(Wo, wob, 262144);
  cast_bf16_k<<<4096, 256, 0, stream>>>(W1, w1b, 1048576);
  cast_bf16_k<<<4096, 256, 0, stream>>>(W2, w2b, 1048576);

  // QKV projection (m97 128^2): Q,K -> qk2 (stride 2048), V -> vT
  gemm_bf16<0, 0, 1, 1><<<64 * 24, 256, 0, stream>>>(xbf, qkvw, nullptr, qk2,
                                                     vT, 8192, 3072, 1024);
  attention_mfma_k<<<2048, 256, 0, stream>>>(qk2, vT, len, concat);
  // output projection -> fp32
  gemm_bf16<0, 0, 0, 0><<<64 * 8, 256, 0, stream>>>(concat, wob, nullptr,
                                                    attno, nullptr,
                                                    8192, 1024, 1024);
  add_ln_k<1><<<8192, 256, 0, stream>>>(x, attno, x1, x1b);
  // FFN1 + bias + relu -> bf16
  gemm_bf16<1, 1, 1, 0><<<64 * 32, 256, 0, stream>>>(x1b, w1b, b1, hidden,
                                                     nullptr, 8192, 4096, 1024);
  // FFN2 + bias -> fp32
  gemm_bf16<1, 0, 0, 0><<<64 * 8, 256, 0, stream>>>(hidden, w2b, b2, ffn2o,
                                                    nullptr, 8192, 1024, 4096);
  add_ln_k<0><<<8192, 256, 0, stream>>>(x1, ffn2o, out, nullptr);
}

// Round 8
// 464.353 us; speedup vs baseline: 1.4624x; 1.0831x over previous
//
#include <hip/hip_runtime.h>
#include <hip/hip_bf16.h>
#include <math.h>

#define B_ 8
#define S_ 1024
#define D_ 1024
#define H_ 16
#define DH_ 64
#define FFN_ 4096
#define NEG_ (-1e9f)
#define EPS_ 1e-5f

typedef float f32x4 __attribute__((ext_vector_type(4)));
typedef short bf16x8 __attribute__((ext_vector_type(8)));

__device__ __forceinline__ ushort f2b(float f) {
  __hip_bfloat16 h = __float2bfloat16(f);  // RNE
  return *reinterpret_cast<ushort*>(&h);
}
__device__ __forceinline__ float b2f(ushort u) {
  return __uint_as_float((unsigned)u << 16);
}

__device__ __forceinline__ void gload16(const void* g, void* l) {
  auto* lp = (__attribute__((address_space(3))) unsigned*)(uintptr_t)(l);
  __builtin_amdgcn_global_load_lds(
      (const __attribute__((address_space(1))) unsigned*)g, lp, 16, 0, 0);
}

// XOR swizzle for [*][64]-ushort LDS tiles (128B row stride)
__device__ __forceinline__ void* swz_ptr(void* base, int row, int col) {
  int byte = (row << 7) + (col << 1);
  byte ^= (row & 7) << 4;
  return (char*)base + byte;
}

// ---------------------------------------------------------------------------
// merged prep: cast x/Wo/W1/W2 to bf16 + pack qkv weights transposed
// ---------------------------------------------------------------------------
__global__ __launch_bounds__(256) void prep_k(
    const float* __restrict__ x, const float* __restrict__ Wq,
    const float* __restrict__ Wk, const float* __restrict__ Wv,
    const float* __restrict__ Wo, const float* __restrict__ W1,
    const float* __restrict__ W2, ushort* __restrict__ xbf,
    ushort* __restrict__ qkvw, ushort* __restrict__ wob,
    ushort* __restrict__ w1b, ushort* __restrict__ w2b) {
  const int blk = blockIdx.x, t = threadIdx.x;
  if (blk < 8192) {  // x: 2M float4
    int i = blk * 256 + t;
    float4 v = ((const float4*)x)[i];
    ushort4 o;
    o.x = f2b(v.x); o.y = f2b(v.y); o.z = f2b(v.z); o.w = f2b(v.w);
    ((ushort4*)xbf)[i] = o;
  } else if (blk < 8192 + 12288) {  // qkvT pack: 3M scalars
    int idx = (blk - 8192) * 256 + t;
    int e = idx & 63, k = (idx >> 6) & 1023;
    int h = (idx >> 16) & 15, which = idx >> 20;
    const float* W = (which == 0) ? Wq : (which == 1 ? Wk : Wv);
    float v = W[((size_t)h * D_ + k) * DH_ + e];
    qkvw[((size_t)which * 1024 + h * 64 + e) * 1024 + k] = f2b(v);
  } else if (blk < 8192 + 12288 + 1024) {  // Wo: 256K float4
    int i = (blk - 8192 - 12288) * 256 + t;
    float4 v = ((const float4*)Wo)[i];
    ushort4 o;
    o.x = f2b(v.x); o.y = f2b(v.y); o.z = f2b(v.z); o.w = f2b(v.w);
    ((ushort4*)wob)[i] = o;
  } else if (blk < 8192 + 12288 + 1024 + 4096) {  // W1: 1M float4
    int i = (blk - 8192 - 12288 - 1024) * 256 + t;
    float4 v = ((const float4*)W1)[i];
    ushort4 o;
    o.x = f2b(v.x); o.y = f2b(v.y); o.z = f2b(v.z); o.w = f2b(v.w);
    ((ushort4*)w1b)[i] = o;
  } else {  // W2: 1M float4
    int i = (blk - 8192 - 12288 - 1024 - 4096) * 256 + t;
    float4 v = ((const float4*)W2)[i];
    ushort4 o;
    o.x = f2b(v.x); o.y = f2b(v.y); o.z = f2b(v.z); o.w = f2b(v.w);
    ((ushort4*)w2b)[i] = o;
  }
}

// ---------------------------------------------------------------------------
// bf16 MFMA GEMM, 2-phase double-buffered (T3+T4 minimum recipe):
// C[M][N] = act(A[M][K] @ Bt[N][K]^T + bias). 128x128 tile, BK=64,
// 256 thr = 4 waves (2x2). STAGE(t+1) issued BEFORE compute(t); one
// vmcnt(0)+barrier per K-step. VSPLIT: QKV epilogue (Q,K -> stride 2048,
// V -> vT[b][h][e][s]).
// ---------------------------------------------------------------------------
template <int BIAS, int RELU, int OUT_BF16, int VSPLIT>
__global__ __launch_bounds__(256) void gemm_bf16(
    const ushort* __restrict__ A, const ushort* __restrict__ Bt,
    const float* __restrict__ bias, void* __restrict__ C,
    ushort* __restrict__ vT, int M, int N, int K) {
  __shared__ ushort Al[2][128 * 64];
  __shared__ ushort Bl[2][128 * 64];
  const int nb = N >> 7;
  const int bm = blockIdx.x / nb, bn = blockIdx.x % nb;
  const int t = threadIdx.x;
  const int lane = t & 63;
  const int wid = t >> 6, wr = wid >> 1, wc = wid & 1;
  const int row0 = bm << 7, col0 = bn << 7;
  const size_t Kb = (size_t)K * 2;
  const int NT = K >> 6;

  const char* Abase = (const char*)A + (size_t)row0 * Kb;
  const char* Bbase = (const char*)Bt + (size_t)col0 * Kb;

  f32x4 acc[4][4] = {};
  const int o0 = t * 16;
  const int lrow = lane & 15, lkb = (lane >> 4) * 8;

  auto STAGE = [&](int buf, int kt) {
#pragma unroll
    for (int i = 0; i < 4; i++) {
      int ob = o0 + i * 4096;
      int row = ob >> 7, inrow = ob & 127;
      const char* ga = Abase + (size_t)row * Kb + kt * 128 + inrow;
      const char* gb = Bbase + (size_t)row * Kb + kt * 128 + inrow;
      gload16(ga, (char*)&Al[buf][0] + ob);
      gload16(gb, (char*)&Bl[buf][0] + ob);
    }
  };
  auto COMPUTE = [&](int buf) {
#pragma unroll
    for (int kk = 0; kk < 64; kk += 32) {
      bf16x8 af[4], bfr[4];
      const int lk = lkb + kk;
#pragma unroll
      for (int m = 0; m < 4; m++)
        af[m] = *(const bf16x8*)&Al[buf][(wr * 64 + m * 16 + lrow) * 64 + lk];
#pragma unroll
      for (int n = 0; n < 4; n++)
        bfr[n] = *(const bf16x8*)&Bl[buf][(wc * 64 + n * 16 + lrow) * 64 + lk];
#pragma unroll
      for (int m = 0; m < 4; m++)
#pragma unroll
        for (int n = 0; n < 4; n++)
          acc[m][n] = __builtin_amdgcn_mfma_f32_16x16x32_bf16(
              af[m], bfr[n], acc[m][n], 0, 0, 0);
    }
  };

  STAGE(0, 0);
  __syncthreads();          // implicit vmcnt(0) drain: tile0 ready
  int cur = 0;
  for (int kt = 1; kt < NT; kt++) {
    STAGE(cur ^ 1, kt);     // prefetch next tile (in flight during compute)
    COMPUTE(cur);
    __syncthreads();        // vmcnt(0): prefetch landed; all reads retired
    cur ^= 1;
  }
  COMPUTE(cur);

  const int rbase = row0 + wr * 64 + (lane >> 4) * 4;
  const int cbase = col0 + wc * 64 + (lane & 15);
#pragma unroll
  for (int m = 0; m < 4; m++) {
#pragma unroll
    for (int n = 0; n < 4; n++) {
      int col = cbase + n * 16;
      float bv = BIAS ? bias[col] : 0.0f;
#pragma unroll
      for (int q = 0; q < 4; q++) {
        int row = rbase + m * 16 + q;
        float v = acc[m][n][q] + bv;
        if (RELU) v = fmaxf(v, 0.0f);
        if (VSPLIT) {
          if (col < 2048) {
            ((ushort*)C)[(size_t)row * 2048 + col] = f2b(v);
          } else {
            int h = (col - 2048) >> 6, e = col & 63;
            vT[((((size_t)(row >> 10) * 16 + h) * 64 + e) << 10) +
               (row & 1023)] = f2b(v);
          }
        } else if (OUT_BF16) {
          ((ushort*)C)[(size_t)row * N + col] = f2b(v);
        } else {
          ((float*)C)[(size_t)row * N + col] = v;
        }
      }
    }
  }
}

// ---------------------------------------------------------------------------
// MFMA flash attention with T14 async-STAGE (prefetch next K/V to regs).
// Inputs: qk [B*S][2048] (q|k per head), vT [B][H][64][S]. One block per
// (b, h, 64 q-rows), batch-interleaved block order.
// ---------------------------------------------------------------------------
__global__ __launch_bounds__(256) void attention_mfma_k(
    const ushort* __restrict__ qk, const ushort* __restrict__ vT,
    const int* __restrict__ lens, ushort* __restrict__ concat) {
  __shared__ ushort Qs[64 * 64];
  __shared__ ushort Ks[64 * 64];
  __shared__ ushort Vt[64 * 64];      // [d][key]
  __shared__ ushort Pl[4][16 * 64];   // per-wave P tile [qrow][key]
  const int blk = blockIdx.x;
  const int b = blk & 7, h = (blk >> 3) & 15, q0 = (blk >> 7) << 6;
  const int t = threadIdx.x;
  const int lane = t & 63, w = t >> 6;
  const int lr = lane & 15, lg = lane >> 4;
  const int len_b = lens[b];
  ushort* Plw = &Pl[w][0];
  const ushort* vbase = vT + ((size_t)(b * 16 + h) << 16);  // [64][1024]

  // load Q tile (row-major, swizzled)
#pragma unroll
  for (int i = 0; i < 4; i++) {
    int idx = t + i * 256;
    int r = idx >> 4, eq = idx & 15;
    const ushort* src =
        qk + ((size_t)(b * S_ + q0 + r)) * 2048 + h * 64 + eq * 4;
    *(ushort4*)swz_ptr(Qs, r, eq * 4) = *(const ushort4*)src;
  }
  __syncthreads();
  bf16x8 qf[2];
#pragma unroll
  for (int ds = 0; ds < 2; ds++)
    qf[ds] = *(const bf16x8*)swz_ptr(Qs, w * 16 + lr, lg * 8 + ds * 32);

  float m[4], l[4];
  f32x4 o[4] = {};
#pragma unroll
  for (int q = 0; q < 4; q++) { m[q] = -INFINITY; l[q] = 0.f; }

  ushort4 kreg[4], vreg[4];
  auto LOADT = [&](int j0) {
#pragma unroll
    for (int i = 0; i < 4; i++) {
      int idx = t + i * 256;
      int r = idx >> 4, eq = idx & 15;
      kreg[i] = *(const ushort4*)(qk + ((size_t)(b * S_ + j0 + r)) * 2048 +
                                  1024 + h * 64 + eq * 4);
      vreg[i] = *(const ushort4*)(vbase + (size_t)r * 1024 + j0 + eq * 4);
    }
  };

  const int ntiles = (len_b + 63) >> 6;
  LOADT(0);
  for (int jt = 0; jt < ntiles; jt++) {
    const int j0 = jt << 6;
    __syncthreads();  // previous tile's LDS reads done in all waves
    // write prefetched tile to LDS (swizzled), then issue next prefetch
#pragma unroll
    for (int i = 0; i < 4; i++) {
      int idx = t + i * 256;
      int r = idx >> 4, eq = idx & 15;
      *(ushort4*)swz_ptr(Ks, r, eq * 4) = kreg[i];
      *(ushort4*)swz_ptr(Vt, r, eq * 4) = vreg[i];
    }
    if (jt + 1 < ntiles) LOADT(j0 + 64);  // HBM latency hides under compute
    __syncthreads();

    // QK^T
    f32x4 sacc[4];
    __builtin_amdgcn_s_setprio(1);
#pragma unroll
    for (int n = 0; n < 4; n++) {
      sacc[n] = (f32x4){0.f, 0.f, 0.f, 0.f};
#pragma unroll
      for (int ds = 0; ds < 2; ds++) {
        bf16x8 kf = *(const bf16x8*)swz_ptr(Ks, n * 16 + lr, lg * 8 + ds * 32);
        sacc[n] = __builtin_amdgcn_mfma_f32_16x16x32_bf16(qf[ds], kf, sacc[n],
                                                          0, 0, 0);
      }
    }
    __builtin_amdgcn_s_setprio(0);

    // scale + mask + online softmax
    float p[4][4];
#pragma unroll
    for (int q = 0; q < 4; q++) {
      float s[4];
#pragma unroll
      for (int n = 0; n < 4; n++) {
        s[n] = sacc[n][q] * 0.125f;
        if (j0 + n * 16 + lr >= len_b) s[n] = NEG_;
      }
      float a = fmaxf(fmaxf(s[0], s[1]), fmaxf(s[2], s[3]));
#pragma unroll
      for (int off = 1; off < 16; off <<= 1) a = fmaxf(a, __shfl_xor(a, off));
      float mn = fmaxf(m[q], a);
      float sc = __expf(m[q] - mn);
      float rs = 0.f;
#pragma unroll
      for (int n = 0; n < 4; n++) {
        p[n][q] = __expf(s[n] - mn);
        rs += p[n][q];
      }
#pragma unroll
      for (int off = 1; off < 16; off <<= 1) rs += __shfl_xor(rs, off);
      l[q] = l[q] * sc + rs;
      m[q] = mn;
#pragma unroll
      for (int dt = 0; dt < 4; dt++) o[dt][q] *= sc;
    }

    // P -> bf16 -> per-wave LDS
#pragma unroll
    for (int n = 0; n < 4; n++)
#pragma unroll
      for (int q = 0; q < 4; q++)
        *(ushort*)swz_ptr(Plw, lg * 4 + q, n * 16 + lr) = f2b(p[n][q]);

    // PV
    bf16x8 pf[2];
#pragma unroll
    for (int ks = 0; ks < 2; ks++)
      pf[ks] = *(const bf16x8*)swz_ptr(Plw, lr, lg * 8 + ks * 32);
    __builtin_amdgcn_s_setprio(1);
#pragma unroll
    for (int dt = 0; dt < 4; dt++) {
#pragma unroll
      for (int ks = 0; ks < 2; ks++) {
        bf16x8 vf = *(const bf16x8*)swz_ptr(Vt, dt * 16 + lr, lg * 8 + ks * 32);
        o[dt] = __builtin_amdgcn_mfma_f32_16x16x32_bf16(pf[ks], vf, o[dt],
                                                        0, 0, 0);
      }
    }
    __builtin_amdgcn_s_setprio(0);
  }

#pragma unroll
  for (int q = 0; q < 4; q++) {
    float inv = 1.0f / l[q];
    size_t row = (size_t)(b * S_ + q0 + w * 16 + lg * 4 + q);
#pragma unroll
    for (int dt = 0; dt < 4; dt++)
      concat[row * 1024 + h * 64 + dt * 16 + lr] = f2b(o[dt][q] * inv);
  }
}

// ---------------------------------------------------------------------------
// y = LayerNorm(a + r); optionally also write bf16 copy yb
// ---------------------------------------------------------------------------
template <int WBF>
__global__ __launch_bounds__(256) void add_ln_k(const float* __restrict__ a,
                                                const float* __restrict__ r,
                                                float* __restrict__ y,
                                                ushort* __restrict__ yb) {
  const int row = blockIdx.x, t = threadIdx.x;
  const float4 av = ((const float4*)(a + (size_t)row * 1024))[t];
  const float4 rv = ((const float4*)(r + (size_t)row * 1024))[t];
  float v[4] = {av.x + rv.x, av.y + rv.y, av.z + rv.z, av.w + rv.w};
  float s = v[0] + v[1] + v[2] + v[3];
  float q = v[0] * v[0] + v[1] * v[1] + v[2] * v[2] + v[3] * v[3];
#pragma unroll
  for (int off = 1; off < 64; off <<= 1) {
    s += __shfl_xor(s, off);
    q += __shfl_xor(q, off);
  }
  __shared__ float ss[4], sq[4];
  int wave = t >> 6, lane = t & 63;
  if (lane == 0) { ss[wave] = s; sq[wave] = q; }
  __syncthreads();
  s = ss[0] + ss[1] + ss[2] + ss[3];
  q = sq[0] + sq[1] + sq[2] + sq[3];
  float mean = s * (1.f / 1024.f);
  float var = q * (1.f / 1024.f) - mean * mean;
  float inv = 1.0f / sqrtf(var + EPS_);
  float4 yo;
  yo.x = (v[0] - mean) * inv; yo.y = (v[1] - mean) * inv;
  yo.z = (v[2] - mean) * inv; yo.w = (v[3] - mean) * inv;
  ((float4*)(y + (size_t)row * 1024))[t] = yo;
  if (WBF) {
    ushort4 ob;
    ob.x = f2b(yo.x); ob.y = f2b(yo.y); ob.z = f2b(yo.z); ob.w = f2b(yo.w);
    ((ushort4*)(yb + (size_t)row * 1024))[t] = ob;
  }
}

// ---------------------------------------------------------------------------
extern "C" void kernel_launch(void* const* d_in, const int* in_sizes, int n_in,
                              void* d_out, int out_size, void* d_ws, size_t ws_size,
                              hipStream_t stream) {
  const float* x  = (const float*)d_in[0];
  const int* len  = (const int*)d_in[1];
  const float* Wq = (const float*)d_in[2];
  const float* Wk = (const float*)d_in[3];
  const float* Wv = (const float*)d_in[4];
  const float* Wo = (const float*)d_in[5];
  const float* W1 = (const float*)d_in[6];
  const float* b1 = (const float*)d_in[7];
  const float* W2 = (const float*)d_in[8];
  const float* b2 = (const float*)d_in[9];
  float* out = (float*)d_out;

  if (ws_size < (size_t)184 * 1024 * 1024) return;
  char* w = (char*)d_ws;
  ushort* xbf    = (ushort*)(w);                        // 16MB
  ushort* qkvw   = (ushort*)(w + ((size_t)16 << 20));   // 6MB
  ushort* wob    = (ushort*)(w + ((size_t)22 << 20));   // 2MB
  ushort* w1b    = (ushort*)(w + ((size_t)24 << 20));   // 8MB
  ushort* w2b    = (ushort*)(w + ((size_t)32 << 20));   // 8MB
  ushort* qk2    = (ushort*)(w + ((size_t)40 << 20));   // 32MB  [8192][2048]
  ushort* vT     = (ushort*)(w + ((size_t)72 << 20));   // 16MB  [8][16][64][1024]
  ushort* concat = (ushort*)(w + ((size_t)88 << 20));   // 16MB
  float*  attno  = (float*) (w + ((size_t)104 << 20));  // 32MB
  float*  x1     = (float*) (w + ((size_t)136 << 20));  // 32MB
  ushort* x1b    = (ushort*)(w + ((size_t)168 << 20));  // 16MB
  ushort* hidden = (ushort*)(w + ((size_t)40 << 20));   // 64MB (reuse qk2+vT+concat)
  float*  ffn2o  = (float*) (w + ((size_t)104 << 20));  // 32MB (reuse attno)

  prep_k<<<29696, 256, 0, stream>>>(x, Wq, Wk, Wv, Wo, W1, W2,
                                    xbf, qkvw, wob, w1b, w2b);

  // QKV projection: Q,K -> qk2 (stride 2048), V -> vT
  gemm_bf16<0, 0, 1, 1><<<64 * 24, 256, 0, stream>>>(xbf, qkvw, nullptr, qk2,
                                                     vT, 8192, 3072, 1024);
  attention_mfma_k<<<2048, 256, 0, stream>>>(qk2, vT, len, concat);
  // output projection -> fp32
  gemm_bf16<0, 0, 0, 0><<<64 * 8, 256, 0, stream>>>(concat, wob, nullptr,
                                                    attno, nullptr,
                                                    8192, 1024, 1024);
  add_ln_k<1><<<8192, 256, 0, stream>>>(x, attno, x1, x1b);
  // FFN1 + bias + relu -> bf16
  gemm_bf16<1, 1, 1, 0><<<64 * 32, 256, 0, stream>>>(x1b, w1b, b1, hidden,
                                                     nullptr, 8192, 4096, 1024);
  // FFN2 + bias -> fp32
  gemm_bf16<1, 0, 0, 0><<<64 * 8, 256, 0, stream>>>(hidden, w2b, b2, ffn2o,
                                                    nullptr, 8192, 1024, 4096);
  add_ln_k<0><<<8192, 256, 0, stream>>>(x1, ffn2o, out, nullptr);
}

// Round 9
// 436.424 us; speedup vs baseline: 1.5559x; 1.0640x over previous
//
#include <hip/hip_runtime.h>
#include <hip/hip_bf16.h>
#include <math.h>

#define B_ 8
#define S_ 1024
#define D_ 1024
#define H_ 16
#define DH_ 64
#define FFN_ 4096
#define NEG_ (-1e9f)
#define EPS_ 1e-5f

typedef float f32x4 __attribute__((ext_vector_type(4)));
typedef short bf16x8 __attribute__((ext_vector_type(8)));

__device__ __forceinline__ ushort f2b(float f) {
  __hip_bfloat16 h = __float2bfloat16(f);  // RNE
  return *reinterpret_cast<ushort*>(&h);
}
__device__ __forceinline__ float b2f(ushort u) {
  return __uint_as_float((unsigned)u << 16);
}

__device__ __forceinline__ void gload16(const void* g, void* l) {
  auto* lp = (__attribute__((address_space(3))) unsigned*)(uintptr_t)(l);
  __builtin_amdgcn_global_load_lds(
      (const __attribute__((address_space(1))) unsigned*)g, lp, 16, 0, 0);
}

// XOR swizzle for [*][64]-ushort LDS tiles (128B row stride)
__device__ __forceinline__ void* swz_ptr(void* base, int row, int col) {
  int byte = (row << 7) + (col << 1);
  byte ^= (row & 7) << 4;
  return (char*)base + byte;
}

// ---------------------------------------------------------------------------
// merged prep: cast x/Wo/W1/W2 to bf16 + pack qkv weights transposed
// ---------------------------------------------------------------------------
__global__ __launch_bounds__(256) void prep_k(
    const float* __restrict__ x, const float* __restrict__ Wq,
    const float* __restrict__ Wk, const float* __restrict__ Wv,
    const float* __restrict__ Wo, const float* __restrict__ W1,
    const float* __restrict__ W2, ushort* __restrict__ xbf,
    ushort* __restrict__ qkvw, ushort* __restrict__ wob,
    ushort* __restrict__ w1b, ushort* __restrict__ w2b) {
  const int blk = blockIdx.x, t = threadIdx.x;
  if (blk < 8192) {  // x: 2M float4
    int i = blk * 256 + t;
    float4 v = ((const float4*)x)[i];
    ushort4 o;
    o.x = f2b(v.x); o.y = f2b(v.y); o.z = f2b(v.z); o.w = f2b(v.w);
    ((ushort4*)xbf)[i] = o;
  } else if (blk < 8192 + 12288) {  // qkvT pack: 3M scalars
    int idx = (blk - 8192) * 256 + t;
    int e = idx & 63, k = (idx >> 6) & 1023;
    int h = (idx >> 16) & 15, which = idx >> 20;
    const float* W = (which == 0) ? Wq : (which == 1 ? Wk : Wv);
    float v = W[((size_t)h * D_ + k) * DH_ + e];
    qkvw[((size_t)which * 1024 + h * 64 + e) * 1024 + k] = f2b(v);
  } else if (blk < 8192 + 12288 + 1024) {  // Wo: 256K float4
    int i = (blk - 8192 - 12288) * 256 + t;
    float4 v = ((const float4*)Wo)[i];
    ushort4 o;
    o.x = f2b(v.x); o.y = f2b(v.y); o.z = f2b(v.z); o.w = f2b(v.w);
    ((ushort4*)wob)[i] = o;
  } else if (blk < 8192 + 12288 + 1024 + 4096) {  // W1: 1M float4
    int i = (blk - 8192 - 12288 - 1024) * 256 + t;
    float4 v = ((const float4*)W1)[i];
    ushort4 o;
    o.x = f2b(v.x); o.y = f2b(v.y); o.z = f2b(v.z); o.w = f2b(v.w);
    ((ushort4*)w1b)[i] = o;
  } else {  // W2: 1M float4
    int i = (blk - 8192 - 12288 - 1024 - 4096) * 256 + t;
    float4 v = ((const float4*)W2)[i];
    ushort4 o;
    o.x = f2b(v.x); o.y = f2b(v.y); o.z = f2b(v.z); o.w = f2b(v.w);
    ((ushort4*)w2b)[i] = o;
  }
}

// ---------------------------------------------------------------------------
// bf16 MFMA GEMM, 2-phase double-buffered (T3+T4 minimum recipe):
// C[M][N] = act(A[M][K] @ Bt[N][K]^T + bias). 128x128 tile, BK=64,
// 256 thr = 4 waves (2x2). STAGE(t+1) issued BEFORE compute(t); one
// vmcnt(0)+barrier per K-step. VSPLIT: QKV epilogue (Q,K -> stride 2048,
// V -> vT[b][h][e][s]).
// ---------------------------------------------------------------------------
template <int BIAS, int RELU, int OUT_BF16, int VSPLIT>
__global__ __launch_bounds__(256) void gemm_bf16(
    const ushort* __restrict__ A, const ushort* __restrict__ Bt,
    const float* __restrict__ bias, void* __restrict__ C,
    ushort* __restrict__ vT, int M, int N, int K) {
  __shared__ ushort Al[2][128 * 64];
  __shared__ ushort Bl[2][128 * 64];
  const int nb = N >> 7;
  const int bm = blockIdx.x / nb, bn = blockIdx.x % nb;
  const int t = threadIdx.x;
  const int lane = t & 63;
  const int wid = t >> 6, wr = wid >> 1, wc = wid & 1;
  const int row0 = bm << 7, col0 = bn << 7;
  const size_t Kb = (size_t)K * 2;
  const int NT = K >> 6;

  const char* Abase = (const char*)A + (size_t)row0 * Kb;
  const char* Bbase = (const char*)Bt + (size_t)col0 * Kb;

  f32x4 acc[4][4] = {};
  const int o0 = t * 16;
  const int lrow = lane & 15, lkb = (lane >> 4) * 8;

  auto STAGE = [&](int buf, int kt) {
#pragma unroll
    for (int i = 0; i < 4; i++) {
      int ob = o0 + i * 4096;
      int row = ob >> 7, inrow = ob & 127;
      const char* ga = Abase + (size_t)row * Kb + kt * 128 + inrow;
      const char* gb = Bbase + (size_t)row * Kb + kt * 128 + inrow;
      gload16(ga, (char*)&Al[buf][0] + ob);
      gload16(gb, (char*)&Bl[buf][0] + ob);
    }
  };
  auto COMPUTE = [&](int buf) {
#pragma unroll
    for (int kk = 0; kk < 64; kk += 32) {
      bf16x8 af[4], bfr[4];
      const int lk = lkb + kk;
#pragma unroll
      for (int m = 0; m < 4; m++)
        af[m] = *(const bf16x8*)&Al[buf][(wr * 64 + m * 16 + lrow) * 64 + lk];
#pragma unroll
      for (int n = 0; n < 4; n++)
        bfr[n] = *(const bf16x8*)&Bl[buf][(wc * 64 + n * 16 + lrow) * 64 + lk];
#pragma unroll
      for (int m = 0; m < 4; m++)
#pragma unroll
        for (int n = 0; n < 4; n++)
          acc[m][n] = __builtin_amdgcn_mfma_f32_16x16x32_bf16(
              af[m], bfr[n], acc[m][n], 0, 0, 0);
    }
  };

  STAGE(0, 0);
  __syncthreads();          // implicit vmcnt(0) drain: tile0 ready
  int cur = 0;
  for (int kt = 1; kt < NT; kt++) {
    STAGE(cur ^ 1, kt);     // prefetch next tile (in flight during compute)
    COMPUTE(cur);
    __syncthreads();        // vmcnt(0): prefetch landed; all reads retired
    cur ^= 1;
  }
  COMPUTE(cur);

  const int rbase = row0 + wr * 64 + (lane >> 4) * 4;
  const int cbase = col0 + wc * 64 + (lane & 15);
#pragma unroll
  for (int m = 0; m < 4; m++) {
#pragma unroll
    for (int n = 0; n < 4; n++) {
      int col = cbase + n * 16;
      float bv = BIAS ? bias[col] : 0.0f;
#pragma unroll
      for (int q = 0; q < 4; q++) {
        int row = rbase + m * 16 + q;
        float v = acc[m][n][q] + bv;
        if (RELU) v = fmaxf(v, 0.0f);
        if (VSPLIT) {
          if (col < 2048) {
            ((ushort*)C)[(size_t)row * 2048 + col] = f2b(v);
          } else {
            int h = (col - 2048) >> 6, e = col & 63;
            vT[((((size_t)(row >> 10) * 16 + h) * 64 + e) << 10) +
               (row & 1023)] = f2b(v);
          }
        } else if (OUT_BF16) {
          ((ushort*)C)[(size_t)row * N + col] = f2b(v);
        } else {
          ((float*)C)[(size_t)row * N + col] = v;
        }
      }
    }
  }
}

// ---------------------------------------------------------------------------
// MFMA flash attention, swapped-QK^T (lane-local softmax) + T13 defer-max +
// T14 async-STAGE. sacc = mfma(K,Q) => lane holds P[16 keys][q=lane&15];
// row-reduce = 15 in-lane ops + 2 shfl. P->LDS(row=lr) read back as
// A-operand for PV (A/B frags share layout => PV unchanged).
// ---------------------------------------------------------------------------
__global__ __launch_bounds__(256) void attention_mfma_k(
    const ushort* __restrict__ qk, const ushort* __restrict__ vT,
    const int* __restrict__ lens, ushort* __restrict__ concat) {
  __shared__ ushort Qs[64 * 64];
  __shared__ ushort Ks[64 * 64];
  __shared__ ushort Vt[64 * 64];      // [d][key]
  __shared__ ushort Pl[4][16 * 64];   // per-wave P tile [qrow][key]
  const int blk = blockIdx.x;
  const int b = blk & 7, h = (blk >> 3) & 15, q0 = (blk >> 7) << 6;
  const int t = threadIdx.x;
  const int lane = t & 63, w = t >> 6;
  const int lr = lane & 15, lg = lane >> 4;
  const int lg4 = lg * 4;
  const int len_b = lens[b];
  ushort* Plw = &Pl[w][0];
  const ushort* vbase = vT + ((size_t)(b * 16 + h) << 16);  // [64][1024]

  // load Q tile (row-major, swizzled)
#pragma unroll
  for (int i = 0; i < 4; i++) {
    int idx = t + i * 256;
    int r = idx >> 4, eq = idx & 15;
    const ushort* src =
        qk + ((size_t)(b * S_ + q0 + r)) * 2048 + h * 64 + eq * 4;
    *(ushort4*)swz_ptr(Qs, r, eq * 4) = *(const ushort4*)src;
  }
  __syncthreads();
  bf16x8 qf[2];
#pragma unroll
  for (int ds = 0; ds < 2; ds++)
    qf[ds] = *(const bf16x8*)swz_ptr(Qs, w * 16 + lr, lg * 8 + ds * 32);

  float mrun = -INFINITY, lrun = 0.f;  // for q-row = lr (lane-local)
  f32x4 o[4] = {};                     // o[dt][qi]: q=lg4+qi, d=dt*16+lr

  ushort4 kreg[4], vreg[4];
  auto LOADT = [&](int j0) {
#pragma unroll
    for (int i = 0; i < 4; i++) {
      int idx = t + i * 256;
      int r = idx >> 4, eq = idx & 15;
      kreg[i] = *(const ushort4*)(qk + ((size_t)(b * S_ + j0 + r)) * 2048 +
                                  1024 + h * 64 + eq * 4);
      vreg[i] = *(const ushort4*)(vbase + (size_t)r * 1024 + j0 + eq * 4);
    }
  };

  const int ntiles = (len_b + 63) >> 6;
  LOADT(0);
  for (int jt = 0; jt < ntiles; jt++) {
    const int j0 = jt << 6;
    __syncthreads();  // previous tile's LDS reads done in all waves
#pragma unroll
    for (int i = 0; i < 4; i++) {
      int idx = t + i * 256;
      int r = idx >> 4, eq = idx & 15;
      *(ushort4*)swz_ptr(Ks, r, eq * 4) = kreg[i];
      *(ushort4*)swz_ptr(Vt, r, eq * 4) = vreg[i];
    }
    if (jt + 1 < ntiles) LOADT(j0 + 64);  // HBM latency hides under compute
    __syncthreads();

    // QK^T swapped: sacc[mb] = K[mb-tile] x Q => D[key][q]
    f32x4 sacc[4];
    __builtin_amdgcn_s_setprio(1);
#pragma unroll
    for (int mb = 0; mb < 4; mb++) {
      sacc[mb] = (f32x4){0.f, 0.f, 0.f, 0.f};
#pragma unroll
      for (int ds = 0; ds < 2; ds++) {
        bf16x8 kf = *(const bf16x8*)swz_ptr(Ks, mb * 16 + lr, lg * 8 + ds * 32);
        sacc[mb] = __builtin_amdgcn_mfma_f32_16x16x32_bf16(kf, qf[ds], sacc[mb],
                                                           0, 0, 0);
      }
    }
    __builtin_amdgcn_s_setprio(0);

    // lane-local softmax for q-row = lr; lane's keys = mb*16 + lg4 + qi
    float p[4][4];
    float pmax = -INFINITY;
#pragma unroll
    for (int mb = 0; mb < 4; mb++)
#pragma unroll
      for (int qi = 0; qi < 4; qi++) {
        float v = sacc[mb][qi] * 0.125f;
        if (j0 + mb * 16 + lg4 + qi >= len_b) v = NEG_;
        p[mb][qi] = v;
        pmax = fmaxf(pmax, v);
      }
    pmax = fmaxf(pmax, __shfl_xor(pmax, 16));
    pmax = fmaxf(pmax, __shfl_xor(pmax, 32));
    if (!__all(pmax - mrun <= 8.0f)) {  // T13 defer-max
      float mnew = fmaxf(mrun, pmax);
      float sc = __expf(mrun - mnew);
      mrun = mnew;
      lrun *= sc;
      // broadcast sc to this lane's o q-rows (q = lg4+qi owned by lr'=lg4+qi)
#pragma unroll
      for (int qi = 0; qi < 4; qi++) {
        float scq = __shfl(sc, (lg << 4) + lg4 + qi);
#pragma unroll
        for (int dt = 0; dt < 4; dt++) o[dt][qi] *= scq;
      }
    }
    float rs = 0.f;
#pragma unroll
    for (int mb = 0; mb < 4; mb++)
#pragma unroll
      for (int qi = 0; qi < 4; qi++) {
        float e = __expf(p[mb][qi] - mrun);
        p[mb][qi] = e;
        rs += e;
      }
    rs += __shfl_xor(rs, 16);
    rs += __shfl_xor(rs, 32);
    lrun += rs;

    // P -> bf16 -> per-wave LDS: row = lr, keys consecutive in qi
#pragma unroll
    for (int mb = 0; mb < 4; mb++) {
      ushort2 w0, w1;
      w0.x = f2b(p[mb][0]); w0.y = f2b(p[mb][1]);
      w1.x = f2b(p[mb][2]); w1.y = f2b(p[mb][3]);
      *(ushort2*)swz_ptr(Plw, lr, mb * 16 + lg4) = w0;
      *(ushort2*)swz_ptr(Plw, lr, mb * 16 + lg4 + 2) = w1;
    }

    // PV (unchanged): O[q][d] += P[q][k] V[k][d]
    bf16x8 pf[2];
#pragma unroll
    for (int ks = 0; ks < 2; ks++)
      pf[ks] = *(const bf16x8*)swz_ptr(Plw, lr, lg * 8 + ks * 32);
    __builtin_amdgcn_s_setprio(1);
#pragma unroll
    for (int dt = 0; dt < 4; dt++) {
#pragma unroll
      for (int ks = 0; ks < 2; ks++) {
        bf16x8 vf = *(const bf16x8*)swz_ptr(Vt, dt * 16 + lr, lg * 8 + ks * 32);
        o[dt] = __builtin_amdgcn_mfma_f32_16x16x32_bf16(pf[ks], vf, o[dt],
                                                        0, 0, 0);
      }
    }
    __builtin_amdgcn_s_setprio(0);
  }

  // epilogue: fetch l for each owned q-row, normalize, store
#pragma unroll
  for (int qi = 0; qi < 4; qi++) {
    float lq = __shfl(lrun, (lg << 4) + lg4 + qi);
    float inv = 1.0f / lq;
    size_t row = (size_t)(b * S_ + q0 + w * 16 + lg4 + qi);
#pragma unroll
    for (int dt = 0; dt < 4; dt++)
      concat[row * 1024 + h * 64 + dt * 16 + lr] = f2b(o[dt][qi] * inv);
  }
}

// ---------------------------------------------------------------------------
// y = LayerNorm(a + r); optionally also write bf16 copy yb
// ---------------------------------------------------------------------------
template <int WBF>
__global__ __launch_bounds__(256) void add_ln_k(const float* __restrict__ a,
                                                const float* __restrict__ r,
                                                float* __restrict__ y,
                                                ushort* __restrict__ yb) {
  const int row = blockIdx.x, t = threadIdx.x;
  const float4 av = ((const float4*)(a + (size_t)row * 1024))[t];
  const float4 rv = ((const float4*)(r + (size_t)row * 1024))[t];
  float v[4] = {av.x + rv.x, av.y + rv.y, av.z + rv.z, av.w + rv.w};
  float s = v[0] + v[1] + v[2] + v[3];
  float q = v[0] * v[0] + v[1] * v[1] + v[2] * v[2] + v[3] * v[3];
#pragma unroll
  for (int off = 1; off < 64; off <<= 1) {
    s += __shfl_xor(s, off);
    q += __shfl_xor(q, off);
  }
  __shared__ float ss[4], sq[4];
  int wave = t >> 6, lane = t & 63;
  if (lane == 0) { ss[wave] = s; sq[wave] = q; }
  __syncthreads();
  s = ss[0] + ss[1] + ss[2] + ss[3];
  q = sq[0] + sq[1] + sq[2] + sq[3];
  float mean = s * (1.f / 1024.f);
  float var = q * (1.f / 1024.f) - mean * mean;
  float inv = 1.0f / sqrtf(var + EPS_);
  float4 yo;
  yo.x = (v[0] - mean) * inv; yo.y = (v[1] - mean) * inv;
  yo.z = (v[2] - mean) * inv; yo.w = (v[3] - mean) * inv;
  ((float4*)(y + (size_t)row * 1024))[t] = yo;
  if (WBF) {
    ushort4 ob;
    ob.x = f2b(yo.x); ob.y = f2b(yo.y); ob.z = f2b(yo.z); ob.w = f2b(yo.w);
    ((ushort4*)(yb + (size_t)row * 1024))[t] = ob;
  }
}

// ---------------------------------------------------------------------------
extern "C" void kernel_launch(void* const* d_in, const int* in_sizes, int n_in,
                              void* d_out, int out_size, void* d_ws, size_t ws_size,
                              hipStream_t stream) {
  const float* x  = (const float*)d_in[0];
  const int* len  = (const int*)d_in[1];
  const float* Wq = (const float*)d_in[2];
  const float* Wk = (const float*)d_in[3];
  const float* Wv = (const float*)d_in[4];
  const float* Wo = (const float*)d_in[5];
  const float* W1 = (const float*)d_in[6];
  const float* b1 = (const float*)d_in[7];
  const float* W2 = (const float*)d_in[8];
  const float* b2 = (const float*)d_in[9];
  float* out = (float*)d_out;

  if (ws_size < (size_t)184 * 1024 * 1024) return;
  char* w = (char*)d_ws;
  ushort* xbf    = (ushort*)(w);                        // 16MB
  ushort* qkvw   = (ushort*)(w + ((size_t)16 << 20));   // 6MB
  ushort* wob    = (ushort*)(w + ((size_t)22 << 20));   // 2MB
  ushort* w1b    = (ushort*)(w + ((size_t)24 << 20));   // 8MB
  ushort* w2b    = (ushort*)(w + ((size_t)32 << 20));   // 8MB
  ushort* qk2    = (ushort*)(w + ((size_t)40 << 20));   // 32MB  [8192][2048]
  ushort* vT     = (ushort*)(w + ((size_t)72 << 20));   // 16MB  [8][16][64][1024]
  ushort* concat = (ushort*)(w + ((size_t)88 << 20));   // 16MB
  float*  attno  = (float*) (w + ((size_t)104 << 20));  // 32MB
  float*  x1     = (float*) (w + ((size_t)136 << 20));  // 32MB
  ushort* x1b    = (ushort*)(w + ((size_t)168 << 20));  // 16MB
  ushort* hidden = (ushort*)(w + ((size_t)40 << 20));   // 64MB (reuse qk2+vT+concat)
  float*  ffn2o  = (float*) (w + ((size_t)104 << 20));  // 32MB (reuse attno)

  prep_k<<<29696, 256, 0, stream>>>(x, Wq, Wk, Wv, Wo, W1, W2,
                                    xbf, qkvw, wob, w1b, w2b);

  // QKV projection: Q,K -> qk2 (stride 2048), V -> vT
  gemm_bf16<0, 0, 1, 1><<<64 * 24, 256, 0, stream>>>(xbf, qkvw, nullptr, qk2,
                                                     vT, 8192, 3072, 1024);
  attention_mfma_k<<<2048, 256, 0, stream>>>(qk2, vT, len, concat);
  // output projection -> fp32
  gemm_bf16<0, 0, 0, 0><<<64 * 8, 256, 0, stream>>>(concat, wob, nullptr,
                                                    attno, nullptr,
                                                    8192, 1024, 1024);
  add_ln_k<1><<<8192, 256, 0, stream>>>(x, attno, x1, x1b);
  // FFN1 + bias + relu -> bf16
  gemm_bf16<1, 1, 1, 0><<<64 * 32, 256, 0, stream>>>(x1b, w1b, b1, hidden,
                                                     nullptr, 8192, 4096, 1024);
  // FFN2 + bias -> fp32
  gemm_bf16<1, 0, 0, 0><<<64 * 8, 256, 0, stream>>>(hidden, w2b, b2, ffn2o,
                                                    nullptr, 8192, 1024, 4096);
  add_ln_k<0><<<8192, 256, 0, stream>>>(x1, ffn2o, out, nullptr);
}